// Round 5
// baseline (514.777 us; speedup 1.0000x reference)
//
#include <hip/hip_runtime.h>
#include <hip/hip_bf16.h>

#define NN 100000
#define EE 1600000
#define NB_SCAN 391   // ceil(NN/256)

typedef __hip_bfloat16 bf16_t;
typedef int int4v __attribute__((ext_vector_type(4)));

// ---- workspace layout (float offsets) ----
#define FX    0            // x_cont fp32            600000
#define PARB  600000       // params fp32            4465
#define EMB   604480       // N*32 raw (pre-bn1) embeddings
#define PBUF  3804480      // N*32  P' (bn1+Wmsg folded)
#define QBUF  7004480      // N*32  Q  (bn1+Wmsg folded)
#define ABUF  10204480     // N*32  agg; ALSO aliased as rank[EE] before k_gather
#define SOFF  13404480     // stats: [0:32) sum1 [32:64) sq1 [64:96) sum2 [96:128) sq2, [128] flag
#define DEG   (SOFF + 256)           // 100000 ints
#define ROWP  (DEG + 100000)         // 100001 ints
#define BSUM  (ROWP + 100002)        // 512 ints
#define SRCL  (BSUM + 512)           // 1600000 ints

// ---- param offsets inside PARB ----
#define O_WCONT 0
#define O_BCONT 96
#define O_TCHRG 112
#define O_TPDG  136
#define O_TPV   192
#define O_WCAT  256
#define O_BCAT  640
#define O_WENC  656
#define O_BENC  1680
#define O_GALL  1712
#define O_BEALL 1744
#define O_WMSG  1776
#define O_BMSG  3824
#define O_GCONV 3856
#define O_BECONV 3888
#define O_WOUT1 3920
#define O_BOUT1 4432
#define O_WOUT2 4448
#define O_BOUT2 4464
#define NPAR    4465

__device__ __forceinline__ float bf(unsigned short u) {
    return __uint_as_float(((unsigned)u) << 16);
}
__device__ __forceinline__ float elu(float x) {
    return x > 0.0f ? x : expm1f(x);
}

// ---------------- dtype detection (bf16 vs f32 tensors); single block, no pre-zero ----------------
__global__ __launch_bounds__(64) void k_detect(const unsigned short* __restrict__ w,
                                               int* __restrict__ flag)
{
    int bad = 0;
    for (int i = threadIdx.x; i < 1024; i += 64) {
        unsigned e = (w[i] >> 7) & 0xFFu;
        if (e >= 137u) bad = 1;           // |v| >= 2^10 as bf16 -> impossible for real weights
    }
    unsigned long long m = __ballot(bad);
    if (threadIdx.x == 0) *flag = (m != 0ull) ? 1 : 0;
}

// ---------------- convert float tensors to fp32 workspace; also zero deg & stats ----------------
struct ConvArgs {
    const void* xc;
    const void* p[19];
    const int*  flag;
    float*      fx;
    float*      par;
    int*        deg;
    float*      stats;
};

__global__ __launch_bounds__(256) void k_convert(ConvArgs a)
{
    const int offs[20] = {O_WCONT,O_BCONT,O_TCHRG,O_TPDG,O_TPV,O_WCAT,O_BCAT,O_WENC,
                          O_BENC,O_GALL,O_BEALL,O_WMSG,O_BMSG,O_GCONV,O_BECONV,
                          O_WOUT1,O_BOUT1,O_WOUT2,O_BOUT2,NPAR};
    int b = blockIdx.x, tid = threadIdx.x;
    int g = b * 256 + tid;
    if (g < NN) a.deg[g] = 0;
    if (g < 128) a.stats[g] = 0.0f;
    int f32 = *a.flag;
    if (b < 586) {
        int i0 = b * 1024;
        int lim = i0 + 1024; if (lim > 600000) lim = 600000;
        for (int i = i0 + tid; i < lim; i += 256)
            a.fx[i] = f32 ? ((const float*)a.xc)[i] : bf(((const unsigned short*)a.xc)[i]);
    } else {
        for (int i = tid; i < NPAR; i += 256) {
            int t = 0;
            while (offs[t + 1] <= i) t++;
            int l = i - offs[t];
            const void* s = a.p[t];
            a.par[i] = f32 ? ((const float*)s)[l] : bf(((const unsigned short*)s)[l]);
        }
    }
}

// ---------------- CSR: histogram of dst + arrival rank per edge ----------------
__global__ __launch_bounds__(256) void k_hist(const int* __restrict__ eidx,
                                              int* __restrict__ deg,
                                              int* __restrict__ rank)
{
    int e4 = blockIdx.x * 256 + threadIdx.x;
    if (e4 >= EE / 4) return;
    const int4* dst4 = (const int4*)(eidx + EE);
    int4 d = dst4[e4];
    int4 r;
    r.x = atomicAdd(&deg[d.x], 1);
    r.y = atomicAdd(&deg[d.y], 1);
    r.z = atomicAdd(&deg[d.z], 1);
    r.w = atomicAdd(&deg[d.w], 1);
    ((int4*)rank)[e4] = r;
}

// ---------------- node embedding + fused bn1 stats ----------------
__global__ __launch_bounds__(256) void k_embed(
    const float* __restrict__ fx, const int* __restrict__ x_cat,
    const float* __restrict__ par, float* __restrict__ emb,
    float* __restrict__ stats)
{
    __shared__ float sWc[96], sbc[16], sTc[24], sTp[56], sTv[64];
    __shared__ float sWcat[384], sbcat[16], sWe[1024], sbe[32];
    __shared__ float ls[64];
    int tid = threadIdx.x;
    for (int i = tid; i < 96;   i += 256) sWc[i]   = par[O_WCONT + i];
    for (int i = tid; i < 16;   i += 256) sbc[i]   = par[O_BCONT + i];
    for (int i = tid; i < 24;   i += 256) sTc[i]   = par[O_TCHRG + i];
    for (int i = tid; i < 56;   i += 256) sTp[i]   = par[O_TPDG + i];
    for (int i = tid; i < 64;   i += 256) sTv[i]   = par[O_TPV + i];
    for (int i = tid; i < 384;  i += 256) sWcat[i] = par[O_WCAT + i];
    for (int i = tid; i < 16;   i += 256) sbcat[i] = par[O_BCAT + i];
    for (int i = tid; i < 1024; i += 256) sWe[i]   = par[O_WENC + i];
    for (int i = tid; i < 32;   i += 256) sbe[i]   = par[O_BENC + i];
    if (tid < 64) ls[tid] = 0.0f;
    __syncthreads();

    int n = blockIdx.x * 256 + tid;
    if (n < NN) {
        const float* xr = fx + (size_t)n * 6;
        float x[6];
        #pragma unroll
        for (int k = 0; k < 6; k++) x[k] = xr[k];

        float ec[16];
        #pragma unroll
        for (int j = 0; j < 16; j++) {
            float a = sbc[j];
            #pragma unroll
            for (int k = 0; k < 6; k++) a += x[k] * sWc[k*16 + j];
            ec[j] = elu(a);
        }

        int c0 = x_cat[n*3+0], c1 = x_cat[n*3+1], c2 = x_cat[n*3+2];
        int a0 = c0 < 0 ? -c0 : c0;
        int pi = (a0==1)?0:(a0==2)?1:(a0==11)?2:(a0==13)?3:(a0==22)?4:(a0==130)?5:6;
        int ci_idx = c1 + 1;
        int vi = c2;

        float cin[24];
        #pragma unroll
        for (int k = 0; k < 8; k++) {
            cin[k]      = sTc[ci_idx*8 + k];
            cin[8 + k]  = sTp[pi*8 + k];
            cin[16 + k] = sTv[vi*8 + k];
        }
        float ecat[16];
        #pragma unroll
        for (int j = 0; j < 16; j++) {
            float a = sbcat[j];
            #pragma unroll
            for (int k = 0; k < 24; k++) a += cin[k] * sWcat[k*16 + j];
            ecat[j] = elu(a);
        }

        float in32[32];
        #pragma unroll
        for (int k = 0; k < 16; k++) { in32[k] = ecat[k]; in32[16 + k] = ec[k]; }

        float er[32];
        #pragma unroll
        for (int j = 0; j < 32; j++) {
            float a = sbe[j];
            #pragma unroll
            for (int k = 0; k < 32; k++) a += in32[k] * sWe[k*32 + j];
            er[j] = elu(a);
        }

        float4* o = (float4*)(emb + (size_t)n * 32);
        #pragma unroll
        for (int g = 0; g < 8; g++)
            o[g] = make_float4(er[g*4], er[g*4+1], er[g*4+2], er[g*4+3]);

        #pragma unroll
        for (int c = 0; c < 32; c++) {
            atomicAdd(&ls[c], er[c]);
            atomicAdd(&ls[32 + c], er[c] * er[c]);
        }
    }
    __syncthreads();
    if (tid < 64) atomicAdd(&stats[tid], ls[tid]);
}

// ---------------- stats (used for agg): per-channel sum & sumsq over (N,32) ----------------
__global__ __launch_bounds__(256) void k_stats(const float* __restrict__ xin,
                                               float* __restrict__ outsums, int count)
{
    __shared__ float ls[64];
    int tid = threadIdx.x;
    if (tid < 64) ls[tid] = 0.0f;
    __syncthreads();
    int idx = blockIdx.x * 256 + tid;
    int stride = gridDim.x * 256;
    int c = idx & 31;
    float s = 0.0f, q = 0.0f;
    for (int i = idx; i < count; i += stride) {
        float v = xin[i];
        s += v; q += v * v;
    }
    s += __shfl_xor(s, 32);
    q += __shfl_xor(q, 32);
    if ((tid & 63) < 32) {
        atomicAdd(&ls[c], s);
        atomicAdd(&ls[32 + c], q);
    }
    __syncthreads();
    if (tid < 64) atomicAdd(&outsums[tid], ls[tid]);
}

// ---------------- P' and Q per node (prep1 built in-block from stats) ----------------
__global__ __launch_bounds__(256) void k_pq(
    const float* __restrict__ par, const float* __restrict__ stats,
    const float* __restrict__ emb, float* __restrict__ P, float* __restrict__ Q)
{
    __shared__ float sWP[1024], sWQ[1024], sbP[32], sbQ[32], ssc[32], ssh[32];
    int tid = threadIdx.x;
    if (tid < 32) {
        float mu  = stats[tid] * (1.0f / NN);
        float var = stats[32 + tid] * (1.0f / NN) - mu * mu;
        float s   = par[O_GALL + tid] * rsqrtf(var + 1e-5f);
        ssc[tid] = s;
        ssh[tid] = par[O_BEALL + tid] - mu * s;
    }
    __syncthreads();
    for (int e = tid; e < 1024; e += 256) {
        int k = e >> 5;
        float w1 = par[O_WMSG + e];
        float w2 = par[O_WMSG + 1024 + e];
        sWP[e] = ssc[k] * (w1 - w2);
        sWQ[e] = ssc[k] * w2;
    }
    if (tid < 32) {
        float aP = par[O_BMSG + tid], aQ = 0.0f;
        for (int k = 0; k < 32; k++) {
            float w1 = par[O_WMSG + k*32 + tid];
            float w2 = par[O_WMSG + (k+32)*32 + tid];
            aP += ssh[k] * (w1 - w2);
            aQ += ssh[k] * w2;
        }
        sbP[tid] = aP; sbQ[tid] = aQ;
    }
    __syncthreads();

    int n = blockIdx.x * 256 + tid;
    if (n >= NN) return;

    float e[32];
    const float4* er = (const float4*)(emb + (size_t)n * 32);
    #pragma unroll
    for (int g = 0; g < 8; g++) {
        float4 v = er[g];
        e[g*4+0] = v.x; e[g*4+1] = v.y; e[g*4+2] = v.z; e[g*4+3] = v.w;
    }
    float4* pr = (float4*)(P + (size_t)n * 32);
    float4* qr = (float4*)(Q + (size_t)n * 32);
    #pragma unroll
    for (int cg = 0; cg < 8; cg++) {
        float4 aP = *(const float4*)&sbP[cg*4];
        float4 aQ = *(const float4*)&sbQ[cg*4];
        #pragma unroll
        for (int k = 0; k < 32; k++) {
            float ek = e[k];
            float4 wp = *(const float4*)&sWP[k*32 + cg*4];
            float4 wq = *(const float4*)&sWQ[k*32 + cg*4];
            aP.x += ek * wp.x; aP.y += ek * wp.y; aP.z += ek * wp.z; aP.w += ek * wp.w;
            aQ.x += ek * wq.x; aQ.y += ek * wq.y; aQ.z += ek * wq.z; aQ.w += ek * wq.w;
        }
        pr[cg] = aP;
        qr[cg] = aQ;
    }
}

// ---------------- CSR: per-chunk exclusive scan ----------------
__global__ __launch_bounds__(256) void k_scanA(const int* __restrict__ deg,
                                               int* __restrict__ rowp,
                                               int* __restrict__ bsum)
{
    __shared__ int s[256];
    int tid = threadIdx.x;
    int i = blockIdx.x * 256 + tid;
    int v = (i < NN) ? deg[i] : 0;
    s[tid] = v;
    __syncthreads();
    for (int off = 1; off < 256; off <<= 1) {
        int x = (tid >= off) ? s[tid - off] : 0;
        __syncthreads();
        s[tid] += x;
        __syncthreads();
    }
    if (i < NN) rowp[i] = s[tid] - v;
    if (tid == 255) bsum[blockIdx.x] = s[255];
}

__global__ __launch_bounds__(512) void k_scanB(int* __restrict__ bsum)
{
    __shared__ int s[512];
    int tid = threadIdx.x;
    int v = (tid < NB_SCAN) ? bsum[tid] : 0;
    s[tid] = v;
    __syncthreads();
    for (int off = 1; off < 512; off <<= 1) {
        int x = (tid >= off) ? s[tid - off] : 0;
        __syncthreads();
        s[tid] += x;
        __syncthreads();
    }
    if (tid < NB_SCAN) bsum[tid] = s[tid] - v;   // exclusive
}

__global__ __launch_bounds__(256) void k_scanC(int* __restrict__ rowp,
                                               const int* __restrict__ bsum)
{
    int i = blockIdx.x * 256 + threadIdx.x;
    if (i < NN) rowp[i] += bsum[blockIdx.x];
    if (i == 0) rowp[NN] = EE;
}

// ---------------- CSR: non-atomic scatter via precomputed rank, nt stores ----------------
__global__ __launch_bounds__(256) void k_scatter(const int* __restrict__ eidx,
                                                 const int* __restrict__ rank,
                                                 const int* __restrict__ rowp,
                                                 int* __restrict__ srcl)
{
    int e4 = blockIdx.x * 256 + threadIdx.x;
    if (e4 >= EE / 4) return;
    int4v s = __builtin_nontemporal_load(&((const int4v*)eidx)[e4]);
    int4v d = __builtin_nontemporal_load(&((const int4v*)(eidx + EE))[e4]);
    int4v r = __builtin_nontemporal_load(&((const int4v*)rank)[e4]);
    __builtin_nontemporal_store(s.x, &srcl[rowp[d.x] + r.x]);
    __builtin_nontemporal_store(s.y, &srcl[rowp[d.y] + r.y]);
    __builtin_nontemporal_store(s.z, &srcl[rowp[d.z] + r.z]);
    __builtin_nontemporal_store(s.w, &srcl[rowp[d.w] + r.w]);
}

// ---------------- gather-max: agg[n] = deg>0 ? P[n] + max_{s in adj(n)} Q[s] : 0 ----------------
__global__ __launch_bounds__(256) void k_gather(
    const int* __restrict__ rowp, const int* __restrict__ srcl,
    const float* __restrict__ Q, const float* __restrict__ P,
    float* __restrict__ agg)
{
    int tid = threadIdx.x;
    int group = tid >> 3;        // 32 nodes per block
    int lane8 = tid & 7;         // float4 channel group
    int n = blockIdx.x * 32 + group;
    if (n >= NN) return;
    int beg = rowp[n], end = rowp[n + 1];
    const float4* Q4 = (const float4*)Q;
    float4 m = make_float4(-INFINITY, -INFINITY, -INFINITY, -INFINITY);
    for (int e = beg; e < end; e++) {
        int s = __builtin_nontemporal_load(&srcl[e]);
        float4 q = Q4[(size_t)s * 8 + lane8];
        m.x = fmaxf(m.x, q.x); m.y = fmaxf(m.y, q.y);
        m.z = fmaxf(m.z, q.z); m.w = fmaxf(m.w, q.w);
    }
    float4 o;
    if (end > beg) {
        float4 p = ((const float4*)P)[(size_t)n * 8 + lane8];
        o = make_float4(m.x + p.x, m.y + p.y, m.z + p.z, m.w + p.w);
    } else {
        o = make_float4(0.f, 0.f, 0.f, 0.f);
    }
    ((float4*)agg)[(size_t)n * 8 + lane8] = o;
}

// ---------------- output MLP (bn1 & bn2 scales built in-block) ----------------
__global__ __launch_bounds__(256) void k_out(
    const float* __restrict__ emb, const float* __restrict__ agg,
    const float* __restrict__ par, const float* __restrict__ stats,
    const int* __restrict__ flag, void* __restrict__ out)
{
    __shared__ float sW1[512], sb1[16], sW2[16];
    __shared__ float sc1[32], sh1[32], sc2[32], sh2[32];
    __shared__ float sb2;
    int tid = threadIdx.x;
    for (int i = tid; i < 512; i += 256) sW1[i] = par[O_WOUT1 + i];
    if (tid < 16) { sb1[tid] = par[O_BOUT1 + tid]; sW2[tid] = par[O_WOUT2 + tid]; }
    if (tid < 32) {
        float mu  = stats[tid] * (1.0f / NN);
        float var = stats[32 + tid] * (1.0f / NN) - mu * mu;
        float s   = par[O_GALL + tid] * rsqrtf(var + 1e-5f);
        sc1[tid] = s;
        sh1[tid] = par[O_BEALL + tid] - mu * s;
        float mu2  = stats[64 + tid] * (1.0f / NN);
        float var2 = stats[96 + tid] * (1.0f / NN) - mu2 * mu2;
        float s2   = par[O_GCONV + tid] * rsqrtf(var2 + 1e-5f);
        sc2[tid] = s2;
        sh2[tid] = par[O_BECONV + tid] - mu2 * s2;
    }
    if (tid == 0) sb2 = par[O_BOUT2];
    __syncthreads();

    int n = blockIdx.x * 256 + tid;
    if (n >= NN) return;

    const float4* er = (const float4*)(emb + (size_t)n * 32);
    const float4* ar = (const float4*)(agg + (size_t)n * 32);
    float h[32];
    #pragma unroll
    for (int g = 0; g < 8; g++) {
        float4 ev = er[g];
        float4 av = ar[g];
        h[g*4+0] = ev.x*sc1[g*4+0]+sh1[g*4+0] + av.x*sc2[g*4+0]+sh2[g*4+0];
        h[g*4+1] = ev.y*sc1[g*4+1]+sh1[g*4+1] + av.y*sc2[g*4+1]+sh2[g*4+1];
        h[g*4+2] = ev.z*sc1[g*4+2]+sh1[g*4+2] + av.z*sc2[g*4+2]+sh2[g*4+2];
        h[g*4+3] = ev.w*sc1[g*4+3]+sh1[g*4+3] + av.w*sc2[g*4+3]+sh2[g*4+3];
    }
    float o1[16];
    #pragma unroll
    for (int j = 0; j < 16; j++) {
        float a = sb1[j];
        #pragma unroll
        for (int k = 0; k < 32; k++) a += h[k] * sW1[k*16 + j];
        o1[j] = elu(a);
    }
    float acc = sb2;
    #pragma unroll
    for (int j = 0; j < 16; j++) acc += o1[j] * sW2[j];

    if (*flag) ((float*)out)[n] = acc;
    else       ((bf16_t*)out)[n] = __float2bfloat16(acc);
}

extern "C" void kernel_launch(void* const* d_in, const int* in_sizes, int n_in,
                              void* d_out, int out_size, void* d_ws, size_t ws_size,
                              hipStream_t stream)
{
    const int* x_cat = (const int*)d_in[1];
    const int* eidx  = (const int*)d_in[2];

    float* ws    = (float*)d_ws;
    float* fx    = ws + FX;
    float* par   = ws + PARB;
    float* emb   = ws + EMB;
    float* P     = ws + PBUF;
    float* Q     = ws + QBUF;
    float* agg   = ws + ABUF;
    int*   rank  = (int*)(ws + ABUF);     // aliased: rank dead before agg written
    float* stats = ws + SOFF;
    int*   flag  = (int*)(stats + 128);
    int*   deg   = (int*)(ws + DEG);
    int*   rowp  = (int*)(ws + ROWP);
    int*   bsum  = (int*)(ws + BSUM);
    int*   srcl  = (int*)(ws + SRCL);

    k_detect<<<1, 64, 0, stream>>>((const unsigned short*)d_in[11], flag);

    ConvArgs ca;
    ca.xc = d_in[0];
    for (int t = 0; t < 19; t++) ca.p[t] = d_in[4 + t];
    ca.flag = flag; ca.fx = fx; ca.par = par; ca.deg = deg; ca.stats = stats;
    k_convert<<<587, 256, 0, stream>>>(ca);

    int nb = NB_SCAN;  // 391
    k_hist<<<(EE/4 + 255) / 256, 256, 0, stream>>>(eidx, deg, rank);
    k_embed<<<nb, 256, 0, stream>>>(fx, x_cat, par, emb, stats);
    k_scanA<<<nb, 256, 0, stream>>>(deg, rowp, bsum);
    k_scanB<<<1, 512, 0, stream>>>(bsum);
    k_scanC<<<nb, 256, 0, stream>>>(rowp, bsum);
    k_pq<<<nb, 256, 0, stream>>>(par, stats, emb, P, Q);
    k_scatter<<<(EE/4 + 255) / 256, 256, 0, stream>>>(eidx, rank, rowp, srcl);
    k_gather<<<(NN + 31) / 32, 256, 0, stream>>>(rowp, srcl, Q, P, agg);
    k_stats<<<512, 256, 0, stream>>>(agg, stats + 64, NN * 32);
    k_out<<<nb, 256, 0, stream>>>(emb, agg, par, stats, flag, d_out);
}

// Round 6
// 388.921 us; speedup vs baseline: 1.3236x; 1.3236x over previous
//
#include <hip/hip_runtime.h>
#include <hip/hip_bf16.h>

#define NN 100000
#define EE 1600000
#define NB_SCAN 391   // ceil(NN/256)

typedef __hip_bfloat16 bf16_t;
typedef int int4v __attribute__((ext_vector_type(4)));
typedef float f4 __attribute__((ext_vector_type(4)));

// ---- workspace layout (float offsets) ----
#define FX    0            // x_cont fp32            600000
#define PARB  600000       // params fp32            4465
#define EMB   604480       // N*32 raw (pre-bn1) embeddings
#define PBUF  3804480      // N*32  P' (bn1+Wmsg folded)
#define QBUF  7004480      // N*32  Q  (bn1+Wmsg folded)
#define ABUF  10204480     // N*32  agg; ALSO aliased as rank[EE] before k_gather
#define SOFF  13404480     // stats: [0:32) sum1 [32:64) sq1 [64:96) sum2 [96:128) sq2, [128] flag
#define DEG   (SOFF + 256)           // 100000 ints
#define ROWP  (DEG + 100000)         // 100001 ints
#define BSUM  (ROWP + 100002)        // 512 ints
#define SRCL  (BSUM + 512)           // 1600000 ints

// ---- param offsets inside PARB ----
#define O_WCONT 0
#define O_BCONT 96
#define O_TCHRG 112
#define O_TPDG  136
#define O_TPV   192
#define O_WCAT  256
#define O_BCAT  640
#define O_WENC  656
#define O_BENC  1680
#define O_GALL  1712
#define O_BEALL 1744
#define O_WMSG  1776
#define O_BMSG  3824
#define O_GCONV 3856
#define O_BECONV 3888
#define O_WOUT1 3920
#define O_BOUT1 4432
#define O_WOUT2 4448
#define O_BOUT2 4464
#define NPAR    4465

__device__ __forceinline__ float bf(unsigned short u) {
    return __uint_as_float(((unsigned)u) << 16);
}
__device__ __forceinline__ float elu(float x) {
    return x > 0.0f ? x : expm1f(x);
}
__device__ __forceinline__ f4 elu4(f4 v) {
    f4 r;
    r.x = v.x > 0.0f ? v.x : expm1f(v.x);
    r.y = v.y > 0.0f ? v.y : expm1f(v.y);
    r.z = v.z > 0.0f ? v.z : expm1f(v.z);
    r.w = v.w > 0.0f ? v.w : expm1f(v.w);
    return r;
}

// ---------------- dtype detection (bf16 vs f32 tensors) ----------------
__global__ __launch_bounds__(64) void k_detect(const unsigned short* __restrict__ w,
                                               int* __restrict__ flag)
{
    int bad = 0;
    for (int i = threadIdx.x; i < 1024; i += 64) {
        unsigned e = (w[i] >> 7) & 0xFFu;
        if (e >= 137u) bad = 1;           // |v| >= 2^10 as bf16 -> impossible for real weights
    }
    unsigned long long m = __ballot(bad);
    if (threadIdx.x == 0) *flag = (m != 0ull) ? 1 : 0;
}

// ---------------- convert float tensors to fp32 workspace; also zero deg & stats ----------------
struct ConvArgs {
    const void* xc;
    const void* p[19];
    const int*  flag;
    float*      fx;
    float*      par;
    int*        deg;
    float*      stats;
};

__global__ __launch_bounds__(256) void k_convert(ConvArgs a)
{
    const int offs[20] = {O_WCONT,O_BCONT,O_TCHRG,O_TPDG,O_TPV,O_WCAT,O_BCAT,O_WENC,
                          O_BENC,O_GALL,O_BEALL,O_WMSG,O_BMSG,O_GCONV,O_BECONV,
                          O_WOUT1,O_BOUT1,O_WOUT2,O_BOUT2,NPAR};
    int b = blockIdx.x, tid = threadIdx.x;
    int g = b * 256 + tid;
    if (g < NN) a.deg[g] = 0;
    if (g < 128) a.stats[g] = 0.0f;
    int f32 = *a.flag;
    if (b < 586) {
        int i0 = b * 1024;
        int lim = i0 + 1024; if (lim > 600000) lim = 600000;
        for (int i = i0 + tid; i < lim; i += 256)
            a.fx[i] = f32 ? ((const float*)a.xc)[i] : bf(((const unsigned short*)a.xc)[i]);
    } else {
        for (int i = tid; i < NPAR; i += 256) {
            int t = 0;
            while (offs[t + 1] <= i) t++;
            int l = i - offs[t];
            const void* s = a.p[t];
            a.par[i] = f32 ? ((const float*)s)[l] : bf(((const unsigned short*)s)[l]);
        }
    }
}

// ---------------- CSR: histogram of dst + arrival rank per edge ----------------
__global__ __launch_bounds__(256) void k_hist(const int* __restrict__ eidx,
                                              int* __restrict__ deg,
                                              int* __restrict__ rank)
{
    int e4 = blockIdx.x * 256 + threadIdx.x;
    if (e4 >= EE / 4) return;
    const int4* dst4 = (const int4*)(eidx + EE);
    int4 d = dst4[e4];
    int4 r;
    r.x = atomicAdd(&deg[d.x], 1);
    r.y = atomicAdd(&deg[d.y], 1);
    r.z = atomicAdd(&deg[d.z], 1);
    r.w = atomicAdd(&deg[d.w], 1);
    ((int4*)rank)[e4] = r;
}

// ---------------- node embedding (registers via ext-vectors) ----------------
__global__ __launch_bounds__(256, 1) void k_embed(
    const float* __restrict__ fx, const int* __restrict__ x_cat,
    const float* __restrict__ par, float* __restrict__ emb)
{
    __shared__ f4 sWc4[24];     // W_cont [6][16]
    __shared__ f4 sbc4[4];
    __shared__ f4 sTc4[6], sTp4[14], sTv4[16];
    __shared__ f4 sWcat4[96];   // [24][16]
    __shared__ f4 sbcat4[4];
    __shared__ f4 sWe4[256];    // [32][32]
    __shared__ f4 sbe4[8];
    int tid = threadIdx.x;
    {
        float* s;
        s=(float*)sWc4;   for(int i=tid;i<96;  i+=256) s[i]=par[O_WCONT+i];
        s=(float*)sbc4;   for(int i=tid;i<16;  i+=256) s[i]=par[O_BCONT+i];
        s=(float*)sTc4;   for(int i=tid;i<24;  i+=256) s[i]=par[O_TCHRG+i];
        s=(float*)sTp4;   for(int i=tid;i<56;  i+=256) s[i]=par[O_TPDG+i];
        s=(float*)sTv4;   for(int i=tid;i<64;  i+=256) s[i]=par[O_TPV+i];
        s=(float*)sWcat4; for(int i=tid;i<384; i+=256) s[i]=par[O_WCAT+i];
        s=(float*)sbcat4; for(int i=tid;i<16;  i+=256) s[i]=par[O_BCAT+i];
        s=(float*)sWe4;   for(int i=tid;i<1024;i+=256) s[i]=par[O_WENC+i];
        s=(float*)sbe4;   for(int i=tid;i<32;  i+=256) s[i]=par[O_BENC+i];
    }
    __syncthreads();

    int n = blockIdx.x * 256 + tid;
    if (n >= NN) return;

    const float* xr = fx + (size_t)n * 6;
    float x0=xr[0], x1=xr[1], x2=xr[2], x3=xr[3], x4=xr[4], x5=xr[5];

    f4 ec[4];
    #pragma unroll
    for (int g = 0; g < 4; g++) {
        f4 a = sbc4[g];
        a += x0 * sWc4[0*4+g]; a += x1 * sWc4[1*4+g]; a += x2 * sWc4[2*4+g];
        a += x3 * sWc4[3*4+g]; a += x4 * sWc4[4*4+g]; a += x5 * sWc4[5*4+g];
        ec[g] = elu4(a);
    }

    int c0 = x_cat[n*3+0], c1 = x_cat[n*3+1], c2 = x_cat[n*3+2];
    int a0 = c0 < 0 ? -c0 : c0;
    int pi = (a0==1)?0:(a0==2)?1:(a0==11)?2:(a0==13)?3:(a0==22)?4:(a0==130)?5:6;
    int ci = c1 + 1;

    f4 t0a = sTc4[ci*2],  t0b = sTc4[ci*2+1];
    f4 t1a = sTp4[pi*2],  t1b = sTp4[pi*2+1];
    f4 t2a = sTv4[c2*2],  t2b = sTv4[c2*2+1];

    f4 ecat[4];
    #pragma unroll
    for (int g = 0; g < 4; g++) {
        f4 a = sbcat4[g];
        #pragma unroll
        for (int k = 0; k < 4; k++) a += t0a[k] * sWcat4[(k     )*4+g];
        #pragma unroll
        for (int k = 0; k < 4; k++) a += t0b[k] * sWcat4[(4 + k )*4+g];
        #pragma unroll
        for (int k = 0; k < 4; k++) a += t1a[k] * sWcat4[(8 + k )*4+g];
        #pragma unroll
        for (int k = 0; k < 4; k++) a += t1b[k] * sWcat4[(12 + k)*4+g];
        #pragma unroll
        for (int k = 0; k < 4; k++) a += t2a[k] * sWcat4[(16 + k)*4+g];
        #pragma unroll
        for (int k = 0; k < 4; k++) a += t2b[k] * sWcat4[(20 + k)*4+g];
        ecat[g] = elu4(a);
    }

    // in32 = [ecat(16), ec(16)]
    f4* o = (f4*)(emb + (size_t)n * 32);
    #pragma unroll
    for (int cg = 0; cg < 8; cg++) {
        f4 a = sbe4[cg];
        #pragma unroll
        for (int kg = 0; kg < 4; kg++) {
            #pragma unroll
            for (int k = 0; k < 4; k++)
                a += ecat[kg][k] * sWe4[(kg*4+k)*8 + cg];
        }
        #pragma unroll
        for (int kg = 0; kg < 4; kg++) {
            #pragma unroll
            for (int k = 0; k < 4; k++)
                a += ec[kg][k] * sWe4[(16 + kg*4+k)*8 + cg];
        }
        o[cg] = elu4(a);
    }
}

// ---------------- stats: per-channel sum & sumsq over (N,32) ----------------
__global__ __launch_bounds__(256) void k_stats(const float* __restrict__ xin,
                                               float* __restrict__ outsums, int count)
{
    __shared__ float ls[64];
    int tid = threadIdx.x;
    if (tid < 64) ls[tid] = 0.0f;
    __syncthreads();
    int idx = blockIdx.x * 256 + tid;
    int stride = gridDim.x * 256;
    int c = idx & 31;
    float s = 0.0f, q = 0.0f;
    for (int i = idx; i < count; i += stride) {
        float v = xin[i];
        s += v; q += v * v;
    }
    s += __shfl_xor(s, 32);
    q += __shfl_xor(q, 32);
    if ((tid & 63) < 32) {
        atomicAdd(&ls[c], s);
        atomicAdd(&ls[32 + c], q);
    }
    __syncthreads();
    if (tid < 64) atomicAdd(&outsums[tid], ls[tid]);
}

// ---------------- P' and Q per node (prep1 built in-block from stats) ----------------
__global__ __launch_bounds__(256, 1) void k_pq(
    const float* __restrict__ par, const float* __restrict__ stats,
    const float* __restrict__ emb, float* __restrict__ P, float* __restrict__ Q)
{
    __shared__ f4 sWP4[256], sWQ4[256];
    __shared__ f4 sbP4[8], sbQ4[8];
    __shared__ float ssc[32], ssh[32];
    int tid = threadIdx.x;
    if (tid < 32) {
        float mu  = stats[tid] * (1.0f / NN);
        float var = stats[32 + tid] * (1.0f / NN) - mu * mu;
        float s   = par[O_GALL + tid] * rsqrtf(var + 1e-5f);
        ssc[tid] = s;
        ssh[tid] = par[O_BEALL + tid] - mu * s;
    }
    __syncthreads();
    {
        float* wp = (float*)sWP4;
        float* wq = (float*)sWQ4;
        for (int e = tid; e < 1024; e += 256) {
            int k = e >> 5;
            float w1 = par[O_WMSG + e];
            float w2 = par[O_WMSG + 1024 + e];
            wp[e] = ssc[k] * (w1 - w2);
            wq[e] = ssc[k] * w2;
        }
    }
    if (tid < 32) {
        float aP = par[O_BMSG + tid], aQ = 0.0f;
        for (int k = 0; k < 32; k++) {
            float w1 = par[O_WMSG + k*32 + tid];
            float w2 = par[O_WMSG + (k+32)*32 + tid];
            aP += ssh[k] * (w1 - w2);
            aQ += ssh[k] * w2;
        }
        ((float*)sbP4)[tid] = aP;
        ((float*)sbQ4)[tid] = aQ;
    }
    __syncthreads();

    int n = blockIdx.x * 256 + tid;
    if (n >= NN) return;

    const f4* er = (const f4*)(emb + (size_t)n * 32);
    f4 e[8];
    #pragma unroll
    for (int g = 0; g < 8; g++) e[g] = er[g];

    f4* pr = (f4*)(P + (size_t)n * 32);
    f4* qr = (f4*)(Q + (size_t)n * 32);
    #pragma unroll
    for (int cg = 0; cg < 8; cg++) {
        f4 aP = sbP4[cg];
        f4 aQ = sbQ4[cg];
        #pragma unroll
        for (int kg = 0; kg < 8; kg++) {
            #pragma unroll
            for (int k = 0; k < 4; k++) {
                float ek = e[kg][k];
                aP += ek * sWP4[(kg*4+k)*8 + cg];
                aQ += ek * sWQ4[(kg*4+k)*8 + cg];
            }
        }
        pr[cg] = aP;
        qr[cg] = aQ;
    }
}

// ---------------- CSR: per-chunk exclusive scan ----------------
__global__ __launch_bounds__(256) void k_scanA(const int* __restrict__ deg,
                                               int* __restrict__ rowp,
                                               int* __restrict__ bsum)
{
    __shared__ int s[256];
    int tid = threadIdx.x;
    int i = blockIdx.x * 256 + tid;
    int v = (i < NN) ? deg[i] : 0;
    s[tid] = v;
    __syncthreads();
    for (int off = 1; off < 256; off <<= 1) {
        int x = (tid >= off) ? s[tid - off] : 0;
        __syncthreads();
        s[tid] += x;
        __syncthreads();
    }
    if (i < NN) rowp[i] = s[tid] - v;
    if (tid == 255) bsum[blockIdx.x] = s[255];
}

__global__ __launch_bounds__(512) void k_scanB(int* __restrict__ bsum)
{
    __shared__ int s[512];
    int tid = threadIdx.x;
    int v = (tid < NB_SCAN) ? bsum[tid] : 0;
    s[tid] = v;
    __syncthreads();
    for (int off = 1; off < 512; off <<= 1) {
        int x = (tid >= off) ? s[tid - off] : 0;
        __syncthreads();
        s[tid] += x;
        __syncthreads();
    }
    if (tid < NB_SCAN) bsum[tid] = s[tid] - v;   // exclusive
}

__global__ __launch_bounds__(256) void k_scanC(int* __restrict__ rowp,
                                               const int* __restrict__ bsum)
{
    int i = blockIdx.x * 256 + threadIdx.x;
    if (i < NN) rowp[i] += bsum[blockIdx.x];
    if (i == 0) rowp[NN] = EE;
}

// ---------------- CSR: non-atomic scatter via precomputed rank, nt stores ----------------
__global__ __launch_bounds__(256) void k_scatter(const int* __restrict__ eidx,
                                                 const int* __restrict__ rank,
                                                 const int* __restrict__ rowp,
                                                 int* __restrict__ srcl)
{
    int e4 = blockIdx.x * 256 + threadIdx.x;
    if (e4 >= EE / 4) return;
    int4v s = __builtin_nontemporal_load(&((const int4v*)eidx)[e4]);
    int4v d = __builtin_nontemporal_load(&((const int4v*)(eidx + EE))[e4]);
    int4v r = __builtin_nontemporal_load(&((const int4v*)rank)[e4]);
    __builtin_nontemporal_store(s.x, &srcl[rowp[d.x] + r.x]);
    __builtin_nontemporal_store(s.y, &srcl[rowp[d.y] + r.y]);
    __builtin_nontemporal_store(s.z, &srcl[rowp[d.z] + r.z]);
    __builtin_nontemporal_store(s.w, &srcl[rowp[d.w] + r.w]);
}

// ---------------- gather-max: agg[n] = deg>0 ? P[n] + max_{s in adj(n)} Q[s] : 0 ----------------
__global__ __launch_bounds__(256) void k_gather(
    const int* __restrict__ rowp, const int* __restrict__ srcl,
    const float* __restrict__ Q, const float* __restrict__ P,
    float* __restrict__ agg)
{
    int tid = threadIdx.x;
    int group = tid >> 3;        // 32 nodes per block
    int lane8 = tid & 7;         // float4 channel group
    int n = blockIdx.x * 32 + group;
    if (n >= NN) return;
    int beg = rowp[n], end = rowp[n + 1];
    const float4* Q4 = (const float4*)Q;
    float4 m = make_float4(-INFINITY, -INFINITY, -INFINITY, -INFINITY);
    for (int e = beg; e < end; e++) {
        int s = __builtin_nontemporal_load(&srcl[e]);
        float4 q = Q4[(size_t)s * 8 + lane8];
        m.x = fmaxf(m.x, q.x); m.y = fmaxf(m.y, q.y);
        m.z = fmaxf(m.z, q.z); m.w = fmaxf(m.w, q.w);
    }
    float4 o;
    if (end > beg) {
        float4 p = ((const float4*)P)[(size_t)n * 8 + lane8];
        o = make_float4(m.x + p.x, m.y + p.y, m.z + p.z, m.w + p.w);
    } else {
        o = make_float4(0.f, 0.f, 0.f, 0.f);
    }
    ((float4*)agg)[(size_t)n * 8 + lane8] = o;
}

// ---------------- output MLP (bn1 & bn2 scales built in-block) ----------------
__global__ __launch_bounds__(256, 1) void k_out(
    const float* __restrict__ emb, const float* __restrict__ agg,
    const float* __restrict__ par, const float* __restrict__ stats,
    const int* __restrict__ flag, void* __restrict__ out)
{
    __shared__ f4 sW14[128];    // [32][16]
    __shared__ f4 sb14[4], sW24[4];
    __shared__ f4 sc14[8], sh14[8], sc24[8], sh24[8];
    __shared__ float sb2s;
    int tid = threadIdx.x;
    {
        float* s = (float*)sW14;
        for (int i = tid; i < 512; i += 256) s[i] = par[O_WOUT1 + i];
    }
    if (tid < 16) {
        ((float*)sb14)[tid] = par[O_BOUT1 + tid];
        ((float*)sW24)[tid] = par[O_WOUT2 + tid];
    }
    if (tid < 32) {
        float mu  = stats[tid] * (1.0f / NN);
        float var = stats[32 + tid] * (1.0f / NN) - mu * mu;
        float s   = par[O_GALL + tid] * rsqrtf(var + 1e-5f);
        ((float*)sc14)[tid] = s;
        ((float*)sh14)[tid] = par[O_BEALL + tid] - mu * s;
        float mu2  = stats[64 + tid] * (1.0f / NN);
        float var2 = stats[96 + tid] * (1.0f / NN) - mu2 * mu2;
        float s2   = par[O_GCONV + tid] * rsqrtf(var2 + 1e-5f);
        ((float*)sc24)[tid] = s2;
        ((float*)sh24)[tid] = par[O_BECONV + tid] - mu2 * s2;
    }
    if (tid == 0) sb2s = par[O_BOUT2];
    __syncthreads();

    int n = blockIdx.x * 256 + tid;
    if (n >= NN) return;

    const f4* er = (const f4*)(emb + (size_t)n * 32);
    const f4* ar = (const f4*)(agg + (size_t)n * 32);
    f4 h[8];
    #pragma unroll
    for (int g = 0; g < 8; g++) {
        f4 ev = er[g];
        f4 av = ar[g];
        h[g] = ev * sc14[g] + sh14[g] + av * sc24[g] + sh24[g];
    }
    f4 o1[4];
    #pragma unroll
    for (int g = 0; g < 4; g++) {
        f4 acc = sb14[g];
        #pragma unroll
        for (int kg = 0; kg < 8; kg++) {
            #pragma unroll
            for (int k = 0; k < 4; k++)
                acc += h[kg][k] * sW14[(kg*4+k)*4 + g];
        }
        o1[g] = elu4(acc);
    }
    float acc = sb2s;
    #pragma unroll
    for (int g = 0; g < 4; g++) {
        f4 p = o1[g] * sW24[g];
        acc += p.x + p.y + p.z + p.w;
    }

    if (*flag) ((float*)out)[n] = acc;
    else       ((bf16_t*)out)[n] = __float2bfloat16(acc);
}

extern "C" void kernel_launch(void* const* d_in, const int* in_sizes, int n_in,
                              void* d_out, int out_size, void* d_ws, size_t ws_size,
                              hipStream_t stream)
{
    const int* x_cat = (const int*)d_in[1];
    const int* eidx  = (const int*)d_in[2];

    float* ws    = (float*)d_ws;
    float* fx    = ws + FX;
    float* par   = ws + PARB;
    float* emb   = ws + EMB;
    float* P     = ws + PBUF;
    float* Q     = ws + QBUF;
    float* agg   = ws + ABUF;
    int*   rank  = (int*)(ws + ABUF);     // aliased: rank dead before agg written
    float* stats = ws + SOFF;
    int*   flag  = (int*)(stats + 128);
    int*   deg   = (int*)(ws + DEG);
    int*   rowp  = (int*)(ws + ROWP);
    int*   bsum  = (int*)(ws + BSUM);
    int*   srcl  = (int*)(ws + SRCL);

    k_detect<<<1, 64, 0, stream>>>((const unsigned short*)d_in[11], flag);

    ConvArgs ca;
    ca.xc = d_in[0];
    for (int t = 0; t < 19; t++) ca.p[t] = d_in[4 + t];
    ca.flag = flag; ca.fx = fx; ca.par = par; ca.deg = deg; ca.stats = stats;
    k_convert<<<587, 256, 0, stream>>>(ca);

    int nb = NB_SCAN;  // 391
    k_hist<<<(EE/4 + 255) / 256, 256, 0, stream>>>(eidx, deg, rank);
    k_embed<<<nb, 256, 0, stream>>>(fx, x_cat, par, emb);
    k_stats<<<512, 256, 0, stream>>>(emb, stats, NN * 32);
    k_scanA<<<nb, 256, 0, stream>>>(deg, rowp, bsum);
    k_scanB<<<1, 512, 0, stream>>>(bsum);
    k_scanC<<<nb, 256, 0, stream>>>(rowp, bsum);
    k_pq<<<nb, 256, 0, stream>>>(par, stats, emb, P, Q);
    k_scatter<<<(EE/4 + 255) / 256, 256, 0, stream>>>(eidx, rank, rowp, srcl);
    k_gather<<<(NN + 31) / 32, 256, 0, stream>>>(rowp, srcl, Q, P, agg);
    k_stats<<<512, 256, 0, stream>>>(agg, stats + 64, NN * 32);
    k_out<<<nb, 256, 0, stream>>>(emb, agg, par, stats, flag, d_out);
}

// Round 7
// 388.132 us; speedup vs baseline: 1.3263x; 1.0020x over previous
//
#include <hip/hip_runtime.h>
#include <hip/hip_bf16.h>

#define NN 100000
#define EE 1600000
#define NB_SCAN 391   // ceil(NN/256)
#define HB 782        // ceil(EE/8/256) hist/scatter blocks (8 edges/thread)

typedef __hip_bfloat16 bf16_t;
typedef int int4v __attribute__((ext_vector_type(4)));
typedef float f4 __attribute__((ext_vector_type(4)));

// ---- workspace layout (float offsets) ----
#define PARB  600000       // params fp32            4465
#define EMB   604480       // N*32 raw (pre-bn1) embeddings
#define PBUF  3804480      // N*32  P' (bn1+Wmsg folded)
#define QBUF  7004480      // N*32  Q  (bn1+Wmsg folded)
#define ABUF  10204480     // N*32  agg; ALSO aliased as rank[EE] before k_gather
#define SOFF  13404480     // stats: [0:32) sum1 [32:64) sq1 [64:96) sum2 [96:128) sq2, [128] flag
#define DEG   (SOFF + 256)           // 100000 ints
#define ROWP  (DEG + 100000)         // 100001 ints
#define BSUM  (ROWP + 100002)        // 512 ints
#define SRCL  (BSUM + 512)           // 1600000 ints

// ---- param offsets inside PARB ----
#define O_WCONT 0
#define O_BCONT 96
#define O_TCHRG 112
#define O_TPDG  136
#define O_TPV   192
#define O_WCAT  256
#define O_BCAT  640
#define O_WENC  656
#define O_BENC  1680
#define O_GALL  1712
#define O_BEALL 1744
#define O_WMSG  1776
#define O_BMSG  3824
#define O_GCONV 3856
#define O_BECONV 3888
#define O_WOUT1 3920
#define O_BOUT1 4432
#define O_WOUT2 4448
#define O_BOUT2 4464
#define NPAR    4465

__device__ __forceinline__ float bf(unsigned short u) {
    return __uint_as_float(((unsigned)u) << 16);
}
__device__ __forceinline__ f4 elu4(f4 v) {
    f4 r;
    r.x = v.x > 0.0f ? v.x : expm1f(v.x);
    r.y = v.y > 0.0f ? v.y : expm1f(v.y);
    r.z = v.z > 0.0f ? v.z : expm1f(v.z);
    r.w = v.w > 0.0f ? v.w : expm1f(v.w);
    return r;
}

// ---------------- dtype detection (bf16 vs f32 tensors) ----------------
__global__ __launch_bounds__(64) void k_detect(const unsigned short* __restrict__ w,
                                               int* __restrict__ flag)
{
    int bad = 0;
    for (int i = threadIdx.x; i < 1024; i += 64) {
        unsigned e = (w[i] >> 7) & 0xFFu;
        if (e >= 137u) bad = 1;           // |v| >= 2^10 as bf16 -> impossible for real weights
    }
    unsigned long long m = __ballot(bad);
    if (threadIdx.x == 0) *flag = (m != 0ull) ? 1 : 0;
}

// ---------------- init: zero deg & stats; block 0 converts params ----------------
struct InitArgs {
    const void* p[19];
    const int*  flag;
    float*      par;
    int*        deg;
    float*      stats;
};

__global__ __launch_bounds__(256) void k_init(InitArgs a)
{
    const int offs[20] = {O_WCONT,O_BCONT,O_TCHRG,O_TPDG,O_TPV,O_WCAT,O_BCAT,O_WENC,
                          O_BENC,O_GALL,O_BEALL,O_WMSG,O_BMSG,O_GCONV,O_BECONV,
                          O_WOUT1,O_BOUT1,O_WOUT2,O_BOUT2,NPAR};
    int b = blockIdx.x, tid = threadIdx.x;
    int g = b * 256 + tid;
    if (g < NN) a.deg[g] = 0;
    if (g < 128) a.stats[g] = 0.0f;
    if (b == 0) {
        int f32 = *a.flag;
        for (int i = tid; i < NPAR; i += 256) {
            int t = 0;
            while (offs[t + 1] <= i) t++;
            int l = i - offs[t];
            const void* s = a.p[t];
            a.par[i] = f32 ? ((const float*)s)[l] : bf(((const unsigned short*)s)[l]);
        }
    }
}

// ---------------- fused A: hist (blocks < HB) | embed (blocks >= HB) ----------------
__global__ __launch_bounds__(256, 1) void k_fusedA(
    const int* __restrict__ eidx, int* __restrict__ deg, int* __restrict__ rank,
    const void* __restrict__ xc, const int* __restrict__ x_cat,
    const float* __restrict__ par, const int* __restrict__ flag,
    float* __restrict__ emb)
{
    __shared__ f4 sWc4[24];     // W_cont [6][16]
    __shared__ f4 sbc4[4];
    __shared__ f4 sTc4[6], sTp4[14], sTv4[16];
    __shared__ f4 sWcat4[96];   // [24][16]
    __shared__ f4 sbcat4[4];
    __shared__ f4 sWe4[256];    // [32][32]
    __shared__ f4 sbe4[8];
    int tid = threadIdx.x;
    int b = blockIdx.x;

    if (b < HB) {
        // ---- histogram of dst + arrival rank; 8 edges per thread ----
        int e8 = b * 256 + tid;
        const int4v* dst4 = (const int4v*)(eidx + EE);
        int4v* rank4 = (int4v*)rank;
        int i0 = e8 * 2, i1 = e8 * 2 + 1;
        if (i0 * 4 < EE) {
            int4v d = __builtin_nontemporal_load(&dst4[i0]);
            int4v r;
            r.x = atomicAdd(&deg[d.x], 1);
            r.y = atomicAdd(&deg[d.y], 1);
            r.z = atomicAdd(&deg[d.z], 1);
            r.w = atomicAdd(&deg[d.w], 1);
            rank4[i0] = r;
        }
        if (i1 * 4 < EE) {
            int4v d = __builtin_nontemporal_load(&dst4[i1]);
            int4v r;
            r.x = atomicAdd(&deg[d.x], 1);
            r.y = atomicAdd(&deg[d.y], 1);
            r.z = atomicAdd(&deg[d.z], 1);
            r.w = atomicAdd(&deg[d.w], 1);
            rank4[i1] = r;
        }
        return;
    }

    // ---- embed path ----
    {
        float* s;
        s=(float*)sWc4;   for(int i=tid;i<96;  i+=256) s[i]=par[O_WCONT+i];
        s=(float*)sbc4;   for(int i=tid;i<16;  i+=256) s[i]=par[O_BCONT+i];
        s=(float*)sTc4;   for(int i=tid;i<24;  i+=256) s[i]=par[O_TCHRG+i];
        s=(float*)sTp4;   for(int i=tid;i<56;  i+=256) s[i]=par[O_TPDG+i];
        s=(float*)sTv4;   for(int i=tid;i<64;  i+=256) s[i]=par[O_TPV+i];
        s=(float*)sWcat4; for(int i=tid;i<384; i+=256) s[i]=par[O_WCAT+i];
        s=(float*)sbcat4; for(int i=tid;i<16;  i+=256) s[i]=par[O_BCAT+i];
        s=(float*)sWe4;   for(int i=tid;i<1024;i+=256) s[i]=par[O_WENC+i];
        s=(float*)sbe4;   for(int i=tid;i<32;  i+=256) s[i]=par[O_BENC+i];
    }
    __syncthreads();

    int n = (b - HB) * 256 + tid;
    if (n >= NN) return;

    float x0,x1,x2,x3,x4,x5;
    if (*flag) {
        const float* xr = (const float*)xc + (size_t)n * 6;
        x0=xr[0]; x1=xr[1]; x2=xr[2]; x3=xr[3]; x4=xr[4]; x5=xr[5];
    } else {
        const unsigned* xr = (const unsigned*)xc + (size_t)n * 3;
        unsigned w0=xr[0], w1=xr[1], w2=xr[2];
        x0=__uint_as_float(w0<<16); x1=__uint_as_float(w0 & 0xFFFF0000u);
        x2=__uint_as_float(w1<<16); x3=__uint_as_float(w1 & 0xFFFF0000u);
        x4=__uint_as_float(w2<<16); x5=__uint_as_float(w2 & 0xFFFF0000u);
    }

    f4 ec[4];
    #pragma unroll
    for (int g = 0; g < 4; g++) {
        f4 a = sbc4[g];
        a += x0 * sWc4[0*4+g]; a += x1 * sWc4[1*4+g]; a += x2 * sWc4[2*4+g];
        a += x3 * sWc4[3*4+g]; a += x4 * sWc4[4*4+g]; a += x5 * sWc4[5*4+g];
        ec[g] = elu4(a);
    }

    int c0 = x_cat[n*3+0], c1 = x_cat[n*3+1], c2 = x_cat[n*3+2];
    int a0 = c0 < 0 ? -c0 : c0;
    int pi = (a0==1)?0:(a0==2)?1:(a0==11)?2:(a0==13)?3:(a0==22)?4:(a0==130)?5:6;
    int ci = c1 + 1;

    f4 t0a = sTc4[ci*2],  t0b = sTc4[ci*2+1];
    f4 t1a = sTp4[pi*2],  t1b = sTp4[pi*2+1];
    f4 t2a = sTv4[c2*2],  t2b = sTv4[c2*2+1];

    f4 ecat[4];
    #pragma unroll
    for (int g = 0; g < 4; g++) {
        f4 a = sbcat4[g];
        #pragma unroll
        for (int k = 0; k < 4; k++) a += t0a[k] * sWcat4[(k     )*4+g];
        #pragma unroll
        for (int k = 0; k < 4; k++) a += t0b[k] * sWcat4[(4 + k )*4+g];
        #pragma unroll
        for (int k = 0; k < 4; k++) a += t1a[k] * sWcat4[(8 + k )*4+g];
        #pragma unroll
        for (int k = 0; k < 4; k++) a += t1b[k] * sWcat4[(12 + k)*4+g];
        #pragma unroll
        for (int k = 0; k < 4; k++) a += t2a[k] * sWcat4[(16 + k)*4+g];
        #pragma unroll
        for (int k = 0; k < 4; k++) a += t2b[k] * sWcat4[(20 + k)*4+g];
        ecat[g] = elu4(a);
    }

    f4* o = (f4*)(emb + (size_t)n * 32);
    #pragma unroll
    for (int cg = 0; cg < 8; cg++) {
        f4 a = sbe4[cg];
        #pragma unroll
        for (int kg = 0; kg < 4; kg++) {
            #pragma unroll
            for (int k = 0; k < 4; k++)
                a += ecat[kg][k] * sWe4[(kg*4+k)*8 + cg];
        }
        #pragma unroll
        for (int kg = 0; kg < 4; kg++) {
            #pragma unroll
            for (int k = 0; k < 4; k++)
                a += ec[kg][k] * sWe4[(16 + kg*4+k)*8 + cg];
        }
        o[cg] = elu4(a);
    }
}

// ---------------- fused B: scanA (blocks < NB_SCAN) | stats1 (512 blocks) ----------------
__global__ __launch_bounds__(256) void k_fusedB(
    const int* __restrict__ deg, int* __restrict__ rowp, int* __restrict__ bsum,
    const float* __restrict__ emb, float* __restrict__ stats)
{
    __shared__ int s[256];
    __shared__ float ls[64];
    int tid = threadIdx.x;
    int b = blockIdx.x;
    if (b < NB_SCAN) {
        int i = b * 256 + tid;
        int v = (i < NN) ? deg[i] : 0;
        s[tid] = v;
        __syncthreads();
        for (int off = 1; off < 256; off <<= 1) {
            int x = (tid >= off) ? s[tid - off] : 0;
            __syncthreads();
            s[tid] += x;
            __syncthreads();
        }
        if (i < NN) rowp[i] = s[tid] - v;
        if (tid == 255) bsum[b] = s[255];
        return;
    }
    // stats over emb
    if (tid < 64) ls[tid] = 0.0f;
    __syncthreads();
    int sb = b - NB_SCAN;                 // 0..511
    int idx = sb * 256 + tid;
    int stride = 512 * 256;
    int c = idx & 31;
    float sum = 0.0f, q = 0.0f;
    for (int i = idx; i < NN * 32; i += stride) {
        float v = emb[i];
        sum += v; q += v * v;
    }
    sum += __shfl_xor(sum, 32);
    q   += __shfl_xor(q, 32);
    if ((tid & 63) < 32) {
        atomicAdd(&ls[c], sum);
        atomicAdd(&ls[32 + c], q);
    }
    __syncthreads();
    if (tid < 64) atomicAdd(&stats[tid], ls[tid]);
}

__global__ __launch_bounds__(512) void k_scanB(int* __restrict__ bsum)
{
    __shared__ int s[512];
    int tid = threadIdx.x;
    int v = (tid < NB_SCAN) ? bsum[tid] : 0;
    s[tid] = v;
    __syncthreads();
    for (int off = 1; off < 512; off <<= 1) {
        int x = (tid >= off) ? s[tid - off] : 0;
        __syncthreads();
        s[tid] += x;
        __syncthreads();
    }
    if (tid < NB_SCAN) bsum[tid] = s[tid] - v;   // exclusive
}

// ---------------- fused C: scanC (blocks < NB_SCAN) | pq (NB_SCAN blocks) ----------------
__global__ __launch_bounds__(256, 1) void k_fusedC(
    int* __restrict__ rowp, const int* __restrict__ bsum,
    const float* __restrict__ par, const float* __restrict__ stats,
    const float* __restrict__ emb, float* __restrict__ P, float* __restrict__ Q)
{
    __shared__ f4 sWP4[256], sWQ4[256];
    __shared__ f4 sbP4[8], sbQ4[8];
    __shared__ float ssc[32], ssh[32];
    int tid = threadIdx.x;
    int b = blockIdx.x;
    if (b < NB_SCAN) {
        int i = b * 256 + tid;
        if (i < NN) rowp[i] += bsum[b];
        if (i == 0) rowp[NN] = EE;
        return;
    }
    // pq path
    if (tid < 32) {
        float mu  = stats[tid] * (1.0f / NN);
        float var = stats[32 + tid] * (1.0f / NN) - mu * mu;
        float s   = par[O_GALL + tid] * rsqrtf(var + 1e-5f);
        ssc[tid] = s;
        ssh[tid] = par[O_BEALL + tid] - mu * s;
    }
    __syncthreads();
    {
        float* wp = (float*)sWP4;
        float* wq = (float*)sWQ4;
        for (int e = tid; e < 1024; e += 256) {
            int k = e >> 5;
            float w1 = par[O_WMSG + e];
            float w2 = par[O_WMSG + 1024 + e];
            wp[e] = ssc[k] * (w1 - w2);
            wq[e] = ssc[k] * w2;
        }
    }
    if (tid < 32) {
        float aP = par[O_BMSG + tid], aQ = 0.0f;
        for (int k = 0; k < 32; k++) {
            float w1 = par[O_WMSG + k*32 + tid];
            float w2 = par[O_WMSG + (k+32)*32 + tid];
            aP += ssh[k] * (w1 - w2);
            aQ += ssh[k] * w2;
        }
        ((float*)sbP4)[tid] = aP;
        ((float*)sbQ4)[tid] = aQ;
    }
    __syncthreads();

    int n = (b - NB_SCAN) * 256 + tid;
    if (n >= NN) return;

    const f4* er = (const f4*)(emb + (size_t)n * 32);
    f4 e[8];
    #pragma unroll
    for (int g = 0; g < 8; g++) e[g] = er[g];

    f4* pr = (f4*)(P + (size_t)n * 32);
    f4* qr = (f4*)(Q + (size_t)n * 32);
    #pragma unroll
    for (int cg = 0; cg < 8; cg++) {
        f4 aP = sbP4[cg];
        f4 aQ = sbQ4[cg];
        #pragma unroll
        for (int kg = 0; kg < 8; kg++) {
            #pragma unroll
            for (int k = 0; k < 4; k++) {
                float ek = e[kg][k];
                aP += ek * sWP4[(kg*4+k)*8 + cg];
                aQ += ek * sWQ4[(kg*4+k)*8 + cg];
            }
        }
        pr[cg] = aP;
        qr[cg] = aQ;
    }
}

// ---------------- CSR: non-atomic scatter via precomputed rank; 8 edges/thread ----------------
__global__ __launch_bounds__(256) void k_scatter(const int* __restrict__ eidx,
                                                 const int* __restrict__ rank,
                                                 const int* __restrict__ rowp,
                                                 int* __restrict__ srcl)
{
    int e8 = blockIdx.x * 256 + threadIdx.x;
    const int4v* src4 = (const int4v*)eidx;
    const int4v* dst4 = (const int4v*)(eidx + EE);
    const int4v* rnk4 = (const int4v*)rank;
    #pragma unroll
    for (int h = 0; h < 2; h++) {
        int i = e8 * 2 + h;
        if (i * 4 < EE) {
            int4v s = __builtin_nontemporal_load(&src4[i]);
            int4v d = __builtin_nontemporal_load(&dst4[i]);
            int4v r = __builtin_nontemporal_load(&rnk4[i]);
            __builtin_nontemporal_store(s.x, &srcl[rowp[d.x] + r.x]);
            __builtin_nontemporal_store(s.y, &srcl[rowp[d.y] + r.y]);
            __builtin_nontemporal_store(s.z, &srcl[rowp[d.z] + r.z]);
            __builtin_nontemporal_store(s.w, &srcl[rowp[d.w] + r.w]);
        }
    }
}

// ---------------- gather-max: one wave per node (8 edge-slices x 8 channel-groups) ----------------
__global__ __launch_bounds__(256) void k_gather(
    const int* __restrict__ rowp, const int* __restrict__ srcl,
    const float* __restrict__ Q, const float* __restrict__ P,
    float* __restrict__ agg)
{
    int tid = threadIdx.x;
    int lane = tid & 63;
    int wave = tid >> 6;
    int n = blockIdx.x * 4 + wave;       // 25000 blocks x 4 waves = 100000
    int slice = lane >> 3;               // 0..7 edge slice
    int cg    = lane & 7;                // channel group
    int beg = rowp[n], end = rowp[n + 1];
    const f4* Q4 = (const f4*)Q;
    f4 m = {-INFINITY, -INFINITY, -INFINITY, -INFINITY};
    for (int e = beg + slice; e < end; e += 8) {
        int s = __builtin_nontemporal_load(&srcl[e]);
        f4 q = Q4[(size_t)s * 8 + cg];
        m.x = fmaxf(m.x, q.x); m.y = fmaxf(m.y, q.y);
        m.z = fmaxf(m.z, q.z); m.w = fmaxf(m.w, q.w);
    }
    #pragma unroll
    for (int off = 8; off < 64; off <<= 1) {
        m.x = fmaxf(m.x, __shfl_xor(m.x, off));
        m.y = fmaxf(m.y, __shfl_xor(m.y, off));
        m.z = fmaxf(m.z, __shfl_xor(m.z, off));
        m.w = fmaxf(m.w, __shfl_xor(m.w, off));
    }
    if (lane < 8) {
        f4 o;
        if (end > beg) {
            f4 p = ((const f4*)P)[(size_t)n * 8 + lane];
            o = m + p;
        } else {
            o = (f4){0.f, 0.f, 0.f, 0.f};
        }
        ((f4*)agg)[(size_t)n * 8 + lane] = o;
    }
}

// ---------------- stats2: per-channel sum & sumsq over agg ----------------
__global__ __launch_bounds__(256) void k_stats(const float* __restrict__ xin,
                                               float* __restrict__ outsums, int count)
{
    __shared__ float ls[64];
    int tid = threadIdx.x;
    if (tid < 64) ls[tid] = 0.0f;
    __syncthreads();
    int idx = blockIdx.x * 256 + tid;
    int stride = gridDim.x * 256;
    int c = idx & 31;
    float s = 0.0f, q = 0.0f;
    for (int i = idx; i < count; i += stride) {
        float v = xin[i];
        s += v; q += v * v;
    }
    s += __shfl_xor(s, 32);
    q += __shfl_xor(q, 32);
    if ((tid & 63) < 32) {
        atomicAdd(&ls[c], s);
        atomicAdd(&ls[32 + c], q);
    }
    __syncthreads();
    if (tid < 64) atomicAdd(&outsums[tid], ls[tid]);
}

// ---------------- output MLP (bn1 & bn2 scales built in-block) ----------------
__global__ __launch_bounds__(256, 1) void k_out(
    const float* __restrict__ emb, const float* __restrict__ agg,
    const float* __restrict__ par, const float* __restrict__ stats,
    const int* __restrict__ flag, void* __restrict__ out)
{
    __shared__ f4 sW14[128];    // [32][16]
    __shared__ f4 sb14[4], sW24[4];
    __shared__ f4 sc14[8], sh14[8], sc24[8], sh24[8];
    __shared__ float sb2s;
    int tid = threadIdx.x;
    {
        float* s = (float*)sW14;
        for (int i = tid; i < 512; i += 256) s[i] = par[O_WOUT1 + i];
    }
    if (tid < 16) {
        ((float*)sb14)[tid] = par[O_BOUT1 + tid];
        ((float*)sW24)[tid] = par[O_WOUT2 + tid];
    }
    if (tid < 32) {
        float mu  = stats[tid] * (1.0f / NN);
        float var = stats[32 + tid] * (1.0f / NN) - mu * mu;
        float s   = par[O_GALL + tid] * rsqrtf(var + 1e-5f);
        ((float*)sc14)[tid] = s;
        ((float*)sh14)[tid] = par[O_BEALL + tid] - mu * s;
        float mu2  = stats[64 + tid] * (1.0f / NN);
        float var2 = stats[96 + tid] * (1.0f / NN) - mu2 * mu2;
        float s2   = par[O_GCONV + tid] * rsqrtf(var2 + 1e-5f);
        ((float*)sc24)[tid] = s2;
        ((float*)sh24)[tid] = par[O_BECONV + tid] - mu2 * s2;
    }
    if (tid == 0) sb2s = par[O_BOUT2];
    __syncthreads();

    int n = blockIdx.x * 256 + tid;
    if (n >= NN) return;

    const f4* er = (const f4*)(emb + (size_t)n * 32);
    const f4* ar = (const f4*)(agg + (size_t)n * 32);
    f4 h[8];
    #pragma unroll
    for (int g = 0; g < 8; g++) {
        f4 ev = er[g];
        f4 av = ar[g];
        h[g] = ev * sc14[g] + sh14[g] + av * sc24[g] + sh24[g];
    }
    f4 o1[4];
    #pragma unroll
    for (int g = 0; g < 4; g++) {
        f4 acc = sb14[g];
        #pragma unroll
        for (int kg = 0; kg < 8; kg++) {
            #pragma unroll
            for (int k = 0; k < 4; k++)
                acc += h[kg][k] * sW14[(kg*4+k)*4 + g];
        }
        o1[g] = elu4(acc);
    }
    float acc = sb2s;
    #pragma unroll
    for (int g = 0; g < 4; g++) {
        f4 p = o1[g] * sW24[g];
        acc += p.x + p.y + p.z + p.w;
    }

    if (*flag) ((float*)out)[n] = acc;
    else       ((bf16_t*)out)[n] = __float2bfloat16(acc);
}

extern "C" void kernel_launch(void* const* d_in, const int* in_sizes, int n_in,
                              void* d_out, int out_size, void* d_ws, size_t ws_size,
                              hipStream_t stream)
{
    const void* x_cont = d_in[0];
    const int* x_cat = (const int*)d_in[1];
    const int* eidx  = (const int*)d_in[2];

    float* ws    = (float*)d_ws;
    float* par   = ws + PARB;
    float* emb   = ws + EMB;
    float* P     = ws + PBUF;
    float* Q     = ws + QBUF;
    float* agg   = ws + ABUF;
    int*   rank  = (int*)(ws + ABUF);     // aliased: rank dead before agg written
    float* stats = ws + SOFF;
    int*   flag  = (int*)(stats + 128);
    int*   deg   = (int*)(ws + DEG);
    int*   rowp  = (int*)(ws + ROWP);
    int*   bsum  = (int*)(ws + BSUM);
    int*   srcl  = (int*)(ws + SRCL);

    k_detect<<<1, 64, 0, stream>>>((const unsigned short*)d_in[11], flag);

    InitArgs ia;
    for (int t = 0; t < 19; t++) ia.p[t] = d_in[4 + t];
    ia.flag = flag; ia.par = par; ia.deg = deg; ia.stats = stats;
    k_init<<<NB_SCAN, 256, 0, stream>>>(ia);

    k_fusedA<<<HB + NB_SCAN, 256, 0, stream>>>(eidx, deg, rank, x_cont, x_cat,
                                               par, flag, emb);
    k_fusedB<<<NB_SCAN + 512, 256, 0, stream>>>(deg, rowp, bsum, emb, stats);
    k_scanB<<<1, 512, 0, stream>>>(bsum);
    k_fusedC<<<NB_SCAN * 2, 256, 0, stream>>>(rowp, bsum, par, stats, emb, P, Q);
    k_scatter<<<HB, 256, 0, stream>>>(eidx, rank, rowp, srcl);
    k_gather<<<NN / 4, 256, 0, stream>>>(rowp, srcl, Q, P, agg);
    k_stats<<<512, 256, 0, stream>>>(agg, stats + 64, NN * 32);
    k_out<<<NB_SCAN, 256, 0, stream>>>(emb, agg, par, stats, flag, d_out);
}